// Round 11
// baseline (140.062 us; speedup 1.0000x reference)
//
#include <hip/hip_runtime.h>
#include <hip/hip_bf16.h>

// RelativeAttention: B=2,H=16,L=2048,D=64, fp32 in/out.
// R12: barrier amortization -- 2 k-tiles per __syncthreads. Ledger: ~69us is
//     invariant under occupancy 2->4 w/SIMD (R4/R8), spill +-7dw (R9/R11),
//     VALU -25% (R11), staging placement (R9); issue (VALU+MFMA) ~46% ->
//     ~54% stall paid per-iteration by ALL waves simultaneously (barrier
//     lockstep). Only lever that divides that fixed cost: fewer, fatter
//     sync groups. Structure: 4 K-bufs + 4 V-bufs (73.7KB dynamic LDS,
//     hipFuncSetAttribute once); group g reads buf-pair (g&1), stages tiles
//     2g+2/2g+3 into the opposite pair (readers done before prev barrier),
//     ONE barrier per 2 tiles (16 vs 32). Per-tile compute byte-identical
//     to R11 (bias-C-init, ones-MFMA rowsum, band logic, LDK=72 layouts);
//     nothing held across barriers. 2 blocks/CU naturally pinned by LDS.
//     Canary: WRITE_SIZE must stay 16384 (no spill).

#define LOG2E 1.44269504088896f

constexpr int Lv = 2048, Dv = 64;
constexpr int BH  = 32;        // B*H
constexpr int BQ  = 128;       // q rows per block (4 pairs x 32)
constexpr int BKT = 64;        // k-tile
constexpr int NQT = Lv / BQ;   // 16
constexpr int NKT = Lv / BKT;  // 32
constexpr int LDK = 72;        // LDS row stride (bf16), +8 pad
constexpr int LDO = 68;        // epilogue combine row stride (f32), +4 pad
constexpr int MAXREL = 8;

constexpr int TILEB   = BKT * LDK * 2;        // 9216 B per K or V buffer
constexpr int KOFF    = 0;                    // 4 K buffers
constexpr int VOFF    = 4 * TILEB;            // 4 V buffers at 36864
constexpr int RBOFF   = 8 * TILEB;            // bias table at 73728
constexpr int DYNLDS  = RBOFF + 128;          // 73856 B dynamic LDS

typedef __bf16 bf16x8 __attribute__((ext_vector_type(8)));
typedef __bf16 bf16x4 __attribute__((ext_vector_type(4)));
typedef float  f32x4  __attribute__((ext_vector_type(4)));

static __device__ __forceinline__ unsigned pack2bf(float a, float b) {
    __bf16 x = (__bf16)a, y = (__bf16)b;
    unsigned short ux = __builtin_bit_cast(unsigned short, x);
    unsigned short uy = __builtin_bit_cast(unsigned short, y);
    return (unsigned)ux | ((unsigned)uy << 16);
}

__global__
__attribute__((amdgpu_flat_work_group_size(512, 512), amdgpu_waves_per_eu(4, 4)))
void relattn_kernel(
    const float* __restrict__ Q, const float* __restrict__ K,
    const float* __restrict__ V, const float* __restrict__ RB,
    float* __restrict__ O)
{
    extern __shared__ __align__(16) unsigned char smem[];
    float* sRB = (float*)(smem + RBOFF);

    const int tid  = threadIdx.x;
    const int w    = tid >> 6;     // wave 0..7
    const int lane = tid & 63;
    const int l16  = lane & 15;
    const int lg   = lane >> 4;    // 0..3
    const int pair = w >> 1;       // 0..3: which 32-q sub-tile
    const int wh   = w & 1;        // 0/1:  which kk half of every k-tile

    const int bh = blockIdx.x & (BH - 1);  // same-bh blocks share XCD (bid%8)
    const int qt = blockIdx.x >> 5;

    const size_t base = (size_t)bh * Lv * Dv;
    const float* Qb = Q + base + (size_t)qt * BQ * Dv;
    const float* Kb = K + base;
    const float* Vb = V + base;
    float*       Ob = O + base + (size_t)qt * BQ * Dv;

    if (tid < 2 * MAXREL + 1) sRB[tid] = RB[tid] * LOG2E;  // log2-domain bias

    // ---- Q B-fragments from global, scale folded in ----
    const float qsc = 0.125f * LOG2E;
    bf16x8 qfrag[2][2];   // [h][s]: n = l16, k = lg*8 + j + 32*s
    #pragma unroll
    for (int h = 0; h < 2; ++h) {
        const float* qrow = Qb + (pair * 32 + h * 16 + l16) * Dv;
        #pragma unroll
        for (int s = 0; s < 2; ++s) {
            const float4 a = *(const float4*)(qrow + lg * 8 + 32 * s);
            const float4 b = *(const float4*)(qrow + lg * 8 + 32 * s + 4);
            bf16x8 f;
            f[0] = (__bf16)(a.x * qsc); f[1] = (__bf16)(a.y * qsc);
            f[2] = (__bf16)(a.z * qsc); f[3] = (__bf16)(a.w * qsc);
            f[4] = (__bf16)(b.x * qsc); f[5] = (__bf16)(b.y * qsc);
            f[6] = (__bf16)(b.z * qsc); f[7] = (__bf16)(b.w * qsc);
            qfrag[h][s] = f;
        }
    }

    // ---- ones A-fragment for the rowsum MFMA ----
    bf16x8 ones;
    #pragma unroll
    for (int j = 0; j < 8; ++j) ones[j] = (__bf16)1.0f;

    f32x4 oacc[2][4];     // [h][t]: partial O[q=l16][d = t*16 + lg*4 + r] (kk half)
    f32x4 lfrag[2];       // [h]: rowsum accumulator via ones-MFMA
    #pragma unroll
    for (int h = 0; h < 2; ++h) {
        #pragma unroll
        for (int r = 0; r < 4; ++r) lfrag[h][r] = 0.f;
        #pragma unroll
        for (int t = 0; t < 4; ++t)
            #pragma unroll
            for (int r = 0; r < 4; ++r) oacc[h][t][r] = 0.f;
    }

    // ---- staging indices (512 threads stage the full tile) ----
    const int kr0 = tid >> 4;              // K: row base (p*32 + kr0), 0..31
    const int kc4 = (tid & 15) * 4;        // K: col (float4)
    const int vkk0 = (tid & 31) * 2;       // V: kk pair (vkk0, vkk0+1)
    const int vd0  = (tid >> 5) * 4;       // V: d range [vd0, vd0+4)
    // kk -> mfma-k bit permutation: [t1,t0,lg1,lg0,r1,r0] -> [t1,lg1,lg0,t0,r1,r0]
    const int vcol = (vkk0 & 35) | ((vkk0 & 12) << 1) | ((vkk0 & 16) >> 2); // even

    float4 kreg[2], vreg[2];   // transient: issue -> convert+stage (same group)

    auto loadKV = [&](int kt) {
        const float* Ks = Kb + (size_t)kt * BKT * Dv;
        const float* Vs = Vb + (size_t)kt * BKT * Dv;
        kreg[0] = *(const float4*)(Ks + kr0 * Dv + kc4);
        kreg[1] = *(const float4*)(Ks + (32 + kr0) * Dv + kc4);
        vreg[0] = *(const float4*)(Vs + vkk0 * Dv + vd0);
        vreg[1] = *(const float4*)(Vs + (vkk0 + 1) * Dv + vd0);
    };
    auto stageKV = [&](int buf) {   // convert + write; all state transient
        __bf16* sKb = (__bf16*)(smem + KOFF + buf * TILEB);
        __bf16* sVb = (__bf16*)(smem + VOFF + buf * TILEB);
        #pragma unroll
        for (int p = 0; p < 2; ++p) {
            bf16x4 pk;
            pk[0] = (__bf16)kreg[p].x; pk[1] = (__bf16)kreg[p].y;
            pk[2] = (__bf16)kreg[p].z; pk[3] = (__bf16)kreg[p].w;
            *(bf16x4*)&sKb[(p * 32 + kr0) * LDK + kc4] = pk;
        }
        #pragma unroll
        for (int j = 0; j < 4; ++j)
            *(unsigned*)&sVb[(vd0 + j) * LDK + vcol] =
                pack2bf(vreg[0][j], vreg[1][j]);
    };

    const int qw0 = qt * BQ + pair * 32;   // pair's first q row
    const int qgl = qw0 + l16;             // lane's q row (h=0; +16 for h=1)

    // ---- one k-tile: QK(+bias in C) -> softmax -> [stage pf] -> rowsum+PV ----
    auto TILE = [&](int kt, int rbuf, int wbuf, int pf) {
        if (pf < NKT) loadKV(pf);          // window = QK + softmax
        __bf16* sKr = (__bf16*)(smem + KOFF + rbuf * TILEB);
        __bf16* sVr = (__bf16*)(smem + VOFF + rbuf * TILEB);

        // sacc init = log2-domain bias (folds bias add into MFMA C)
        const int k0 = kt * BKT + wh * 32;
        f32x4 sacc[2][2];
        #pragma unroll
        for (int h = 0; h < 2; ++h) {
            const int qlo = qw0 + h * 16;
            if (k0 >= qlo + 15 + MAXREL) {               // right of band
                const float bc = sRB[2 * MAXREL];
                #pragma unroll
                for (int tl = 0; tl < 2; ++tl)
                    #pragma unroll
                    for (int r = 0; r < 4; ++r) sacc[h][tl][r] = bc;
            } else if (k0 + 31 + MAXREL <= qlo) {        // left of band
                const float bc = sRB[0];
                #pragma unroll
                for (int tl = 0; tl < 2; ++tl)
                    #pragma unroll
                    for (int r = 0; r < 4; ++r) sacc[h][tl][r] = bc;
            } else {                                     // diagonal band
                const int kkb = k0 + lg * 4 - (qgl + h * 16);
                #pragma unroll
                for (int tl = 0; tl < 2; ++tl) {
                    #pragma unroll
                    for (int r = 0; r < 4; ++r) {
                        int d = kkb + tl * 16 + r;
                        d = d < -MAXREL ? -MAXREL : (d > MAXREL ? MAXREL : d);
                        sacc[h][tl][r] = sRB[d + MAXREL];
                    }
                }
            }
        }

        // S^T = K Q^T + bias on this wave's kk half
        #pragma unroll
        for (int s = 0; s < 2; ++s) {
            #pragma unroll
            for (int tl = 0; tl < 2; ++tl) {
                bf16x8 a = *(const bf16x8*)&sKr[((2 * wh + tl) * 16 + l16) * LDK + lg * 8 + 32 * s];
                sacc[0][tl] = __builtin_amdgcn_mfma_f32_16x16x32_bf16(a, qfrag[0][s], sacc[0][tl], 0, 0, 0);
                sacc[1][tl] = __builtin_amdgcn_mfma_f32_16x16x32_bf16(a, qfrag[1][s], sacc[1][tl], 0, 0, 0);
            }
        }

        // softmax: pure exp2 + pack
        bf16x8 pfrag[2];
        #pragma unroll
        for (int h = 0; h < 2; ++h)
            #pragma unroll
            for (int tl = 0; tl < 2; ++tl)
                #pragma unroll
                for (int r = 0; r < 4; ++r)
                    pfrag[h][tl * 4 + r] =
                        (__bf16)__builtin_amdgcn_exp2f(sacc[h][tl][r]);

        // stage prefetched tile into the free pair (ds_writes overlap PV)
        if (pf < NKT) stageKV(wbuf);

        // rowsum on the matrix pipe
        lfrag[0] = __builtin_amdgcn_mfma_f32_16x16x32_bf16(ones, pfrag[0], lfrag[0], 0, 0, 0);
        lfrag[1] = __builtin_amdgcn_mfma_f32_16x16x32_bf16(ones, pfrag[1], lfrag[1], 0, 0, 0);

        // O^T += V^T(kk half) P^T
        #pragma unroll
        for (int t = 0; t < 4; ++t) {
            bf16x8 vf = *(const bf16x8*)&sVr[(t * 16 + l16) * LDK + lg * 8 + 32 * wh];
            oacc[0][t] = __builtin_amdgcn_mfma_f32_16x16x32_bf16(vf, pfrag[0], oacc[0][t], 0, 0, 0);
            oacc[1][t] = __builtin_amdgcn_mfma_f32_16x16x32_bf16(vf, pfrag[1], oacc[1][t], 0, 0, 0);
        }
    };

    // ---- prologue: stage tiles 0,1 into bufs 0,1 ----
    loadKV(0); stageKV(0);
    loadKV(1); stageKV(1);
    __syncthreads();

    // ---- main loop: ONE barrier per 2 tiles ----
    for (int g = 0; g < NKT / 2; ++g) {
        const int rp = (g & 1) << 1;          // read pair base: 0 or 2
        const int wp = ((g + 1) & 1) << 1;    // write pair base: 2 or 0
        TILE(2 * g,     rp,     wp,     2 * g + 2);
        TILE(2 * g + 1, rp + 1, wp + 1, 2 * g + 3);
        __syncthreads();   // publishes wp pair; frees rp pair for next group
    }

    // ---- epilogue: combine wave-pair partials via LDS, normalize, store ----
    float lh[2];
    lh[0] = lfrag[0][0];
    lh[1] = lfrag[1][0];

    // (last loop barrier already separates tile reads from smem reuse)
    float* sO = (float*)smem;                          // [4][32][LDO]
    float* sL = (float*)(smem + 4 * 32 * LDO * 4);     // [4][32]
    if (wh == 1) {
        #pragma unroll
        for (int h = 0; h < 2; ++h) {
            #pragma unroll
            for (int t = 0; t < 4; ++t)
                *(f32x4*)&sO[(pair * 32 + h * 16 + l16) * LDO + t * 16 + lg * 4] = oacc[h][t];
            if (lg == 0) sL[pair * 32 + h * 16 + l16] = lh[h];
        }
    }
    __syncthreads();
    if (wh == 0) {
        #pragma unroll
        for (int h = 0; h < 2; ++h) {
            const float lt = lh[h] + sL[pair * 32 + h * 16 + l16];
            const float linv = 1.f / lt;
            float* orow = Ob + (pair * 32 + h * 16 + l16) * Dv;
            #pragma unroll
            for (int t = 0; t < 4; ++t) {
                f32x4 oo = *(const f32x4*)&sO[(pair * 32 + h * 16 + l16) * LDO + t * 16 + lg * 4];
                float4 o;
                o.x = (oacc[h][t][0] + oo[0]) * linv;
                o.y = (oacc[h][t][1] + oo[1]) * linv;
                o.z = (oacc[h][t][2] + oo[2]) * linv;
                o.w = (oacc[h][t][3] + oo[3]) * linv;
                *(float4*)(orow + t * 16 + lg * 4) = o;
            }
        }
    }
}

extern "C" void kernel_launch(void* const* d_in, const int* in_sizes, int n_in,
                              void* d_out, int out_size, void* d_ws, size_t ws_size,
                              hipStream_t stream) {
    const float* q  = (const float*)d_in[0];
    const float* k  = (const float*)d_in[1];
    const float* v  = (const float*)d_in[2];
    const float* rb = (const float*)d_in[3];
    float* out = (float*)d_out;
    static bool attr_set = false;
    if (!attr_set) {   // one-time, host-side, not stream-ordered (capture-safe)
        hipFuncSetAttribute((const void*)relattn_kernel,
                            hipFuncAttributeMaxDynamicSharedMemorySize, DYNLDS);
        attr_set = true;
    }
    relattn_kernel<<<dim3(BH * NQT), dim3(512), DYNLDS, stream>>>(q, k, v, rb, out);
}